// Round 8
// baseline (183.475 us; speedup 1.0000x reference)
//
#include <hip/hip_runtime.h>
#include <cmath>

// DeepFM R8 = R7 with all address-of-local reinterpret casts removed
// (__builtin_bit_cast / direct vector construction) to kill scratch spills.
// fm: C = E_ti x E_tj^T; z += sum C * W2[j][i] (masked i<j<TS)
// deep: C = E_tt x wdT_kt^T (M=t, N=k); z += relu(C+b).W3[k][t] (masked t<TS)
// w_ffn: deep [0,3200)=t*32+k | fm [3200,8150)=triu i<j | wide [8150,14550)=t*64+f

#define TS 100
#define F  64
#define FD 32
#define RP 112
#define G  8
#define OFF_FM 3200
#define OFF_WIDE 8150
#define VOCAB 100000
#define W2_ELEMS (RP*RP)      // [j:112][i:112] fp32
#define W3_ELEMS (FD*RP)      // [k:32][t:112] fp32
#define WDT_ELEMS (FD*F)      // [k:32][f:64] bf16
#define ESTRIDE (RP*F)        // ushorts per Es buffer (14336 B)

typedef __attribute__((ext_vector_type(8))) short short8;
typedef __attribute__((ext_vector_type(4))) float f32x4;

__device__ __forceinline__ ushort f2bf(float x) {
    uint u = __float_as_uint(x);
    u = (u + 0x7FFFu + ((u >> 16) & 1u)) >> 16;
    return (ushort)u;
}
__device__ __forceinline__ float bf2f(ushort h) {
    return __uint_as_float((uint)h << 16);
}
__device__ __forceinline__ short8 pack8(float4 a, float4 b) {
    short8 r;
    r[0] = (short)f2bf(a.x); r[1] = (short)f2bf(a.y);
    r[2] = (short)f2bf(a.z); r[3] = (short)f2bf(a.w);
    r[4] = (short)f2bf(b.x); r[5] = (short)f2bf(b.y);
    r[6] = (short)f2bf(b.z); r[7] = (short)f2bf(b.w);
    return r;
}

__global__ __launch_bounds__(256)
void emb_cvt(const float* __restrict__ src, ushort* __restrict__ dst, int n8) {
    int i = blockIdx.x * 256 + threadIdx.x;
    if (i >= n8) return;
    const float4* s = reinterpret_cast<const float4*>(src) + (size_t)i * 2;
    short8 r = pack8(s[0], s[1]);
    reinterpret_cast<short8*>(dst)[i] = r;
}

__global__ __launch_bounds__(256)
void prep(const float* __restrict__ w_ffn, const float* __restrict__ w_deep,
          float* __restrict__ W2, float* __restrict__ W3, ushort* __restrict__ wdt) {
    int j = blockIdx.x * 256 + threadIdx.x;
    if (j < W2_ELEMS) {
        int jc = j / RP, i = j % RP;
        float v = 0.f;
        if (i < jc && jc < TS)
            v = w_ffn[OFF_FM + i * (199 - i) / 2 + (jc - i - 1)];
        W2[j] = v;
    } else if (j < W2_ELEMS + W3_ELEMS) {
        int q = j - W2_ELEMS;
        int k = q / RP, t = q % RP;
        W3[q] = (t < TS) ? w_ffn[t * FD + k] : 0.f;
    } else if (j < W2_ELEMS + W3_ELEMS + WDT_ELEMS) {
        int q = j - W2_ELEMS - W3_ELEMS;
        int k = q >> 6, f = q & 63;
        wdt[q] = f2bf(w_deep[f * FD + k]);
    }
}

// fm strip: A = E rows TI*16 (persistent); tiles tj=TI..6; diag tile reuses A as B.
template<int TI>
__device__ __forceinline__ float fm_strip(const char* esp, int c0, int c1,
                                          const float* pW2) {
    short8 A0 = *reinterpret_cast<const short8*>(esp + TI * 2048 + c0);
    short8 A1 = *reinterpret_cast<const short8*>(esp + TI * 2048 + c1);
    float z = 0.f;
    #pragma unroll
    for (int tj = TI; tj < 7; ++tj) {
        short8 B0, B1;
        if (tj == TI) { B0 = A0; B1 = A1; }
        else {
            B0 = *reinterpret_cast<const short8*>(esp + tj * 2048 + c0);
            B1 = *reinterpret_cast<const short8*>(esp + tj * 2048 + c1);
        }
        f32x4 acc = {0.f, 0.f, 0.f, 0.f};
        acc = __builtin_amdgcn_mfma_f32_16x16x32_bf16(A0, B0, acc, 0, 0, 0);
        acc = __builtin_amdgcn_mfma_f32_16x16x32_bf16(A1, B1, acc, 0, 0, 0);
        float4 w = *reinterpret_cast<const float4*>(pW2 + tj * 1792 + TI * 16);
        z += acc[0] * w.x + acc[1] * w.y + acc[2] * w.z + acc[3] * w.w;
    }
    return z;
}

// deep strip: B = wdT rows KT*16 (persistent); A = E rows tt (M=t, N=k).
template<int KT>
__device__ __forceinline__ float deep_strip(const char* esp, const char* wdp,
                                            int c0, int c1, const float* pW3,
                                            float bk) {
    short8 B0 = *reinterpret_cast<const short8*>(wdp + KT * 2048 + c0);
    short8 B1 = *reinterpret_cast<const short8*>(wdp + KT * 2048 + c1);
    float z = 0.f;
    #pragma unroll
    for (int tt = 0; tt < 7; ++tt) {
        short8 A0 = *reinterpret_cast<const short8*>(esp + tt * 2048 + c0);
        short8 A1 = *reinterpret_cast<const short8*>(esp + tt * 2048 + c1);
        f32x4 acc = {0.f, 0.f, 0.f, 0.f};
        acc = __builtin_amdgcn_mfma_f32_16x16x32_bf16(A0, B0, acc, 0, 0, 0);
        acc = __builtin_amdgcn_mfma_f32_16x16x32_bf16(A1, B1, acc, 0, 0, 0);
        float4 w = *reinterpret_cast<const float4*>(pW3 + KT * 1792 + tt * 16);
        z += fmaxf(acc[0] + bk, 0.f) * w.x + fmaxf(acc[1] + bk, 0.f) * w.y
           + fmaxf(acc[2] + bk, 0.f) * w.z + fmaxf(acc[3] + bk, 0.f) * w.w;
    }
    return z;
}

template<bool EMBBF>
__device__ __forceinline__ short8 load8(const float* __restrict__ embf,
                                        const ushort* __restrict__ embh,
                                        int xr, int k8) {
    if (EMBBF) {
        return *reinterpret_cast<const short8*>(embh + (size_t)xr * F + k8 * 8);
    } else {
        const float* s = embf + (size_t)xr * F + k8 * 8;
        float4 a = reinterpret_cast<const float4*>(s)[0];
        float4 c = reinterpret_cast<const float4*>(s)[1];
        return pack8(a, c);
    }
}

// wide dot; w_ffn wide base only 8B-aligned -> float2 loads
__device__ __forceinline__ float dotj(short8 sv, const float* __restrict__ w) {
    const float2* w2 = reinterpret_cast<const float2*>(w);
    float2 wa = w2[0], wb = w2[1], wc = w2[2], wd = w2[3];
    return bf2f((ushort)sv[0]) * wa.x + bf2f((ushort)sv[1]) * wa.y
         + bf2f((ushort)sv[2]) * wb.x + bf2f((ushort)sv[3]) * wb.y
         + bf2f((ushort)sv[4]) * wc.x + bf2f((ushort)sv[5]) * wc.y
         + bf2f((ushort)sv[6]) * wd.x + bf2f((ushort)sv[7]) * wd.y;
}

template<bool EMBBF>
__global__ __launch_bounds__(256, 4)
void deepfm_main(const int* __restrict__ x,
                 const float* __restrict__ embf,
                 const ushort* __restrict__ embh,
                 const float* __restrict__ W2,
                 const float* __restrict__ W3,
                 const ushort* __restrict__ wdt,
                 const float* __restrict__ b_deep,
                 const float* __restrict__ w_ffn,
                 const float* __restrict__ b_ffn,
                 float* __restrict__ out)
{
    __shared__ ushort Es[2][ESTRIDE];   // 2x14336B, XOR-swizzled rows
    __shared__ ushort wdT[FD * F];      // 4096B
    __shared__ int    xsa[G * TS];      // 3200B
    __shared__ float  red[G][4];

    const int tid  = threadIdx.x;
    const int lane = tid & 63;
    const int wave = tid >> 6;
    const int lr   = lane & 15;
    const int lg   = lane >> 4;
    const int b0   = blockIdx.x * G;

    // stage row indices for all G rows + wdT
    for (int j = tid; j < G * TS; j += 256) xsa[j] = x[(size_t)b0 * TS + j];
    {
        int k = tid >> 3, k8 = tid & 7;
        int col = (k8 * 16) ^ ((k & 7) << 4);
        *reinterpret_cast<short8*>(reinterpret_cast<char*>(wdT) + k * 128 + col)
            = *reinterpret_cast<const short8*>(wdt + k * F + k8 * 8);
    }
    __syncthreads();

    // fixed per-thread gather geometry: jobs j = tid, tid+256, tid+512, tid+768
    const int k8  = tid & 7;
    const int r0  = tid >> 3;                 // job rows: r0, r0+32, r0+64, r0+96
    const int sw  = (r0 & 7) << 4;            // (r+32k)&7 == r&7
    const int col = (k8 * 16) ^ sw;
    const bool has3  = tid < 128;             // rows 96..111
    const bool real3 = tid < 32;              // rows 96..99
    const float* ww0 = w_ffn + OFF_WIDE + (r0)      * F + k8 * 8;
    const float* ww1 = w_ffn + OFF_WIDE + (r0 + 32) * F + k8 * 8;
    const float* ww2 = w_ffn + OFF_WIDE + (r0 + 64) * F + k8 * 8;
    const float* ww3 = w_ffn + OFF_WIDE + ((r0 + 96) % RP) * F + k8 * 8;

    // fragment/epilogue bases
    const int c0 = (lg * 16) ^ ((lr & 7) << 4);
    const int c1 = (64 + lg * 16) ^ ((lr & 7) << 4);
    const char* wdp = reinterpret_cast<const char*>(wdT) + lr * 128;
    const float* pW2 = W2 + lr * RP + lg * 4;
    const float* pW3 = W3 + lr * RP + lg * 4;
    const float bk0 = b_deep[lr];
    const float bk1 = b_deep[16 + lr];

    const short8 zero8 = {0, 0, 0, 0, 0, 0, 0, 0};

    // ---- prologue: gather + wide + stage row 0 ----
    float zw_pend;
    {
        short8 v0 = load8<EMBBF>(embf, embh, xsa[r0], k8);
        short8 v1 = load8<EMBBF>(embf, embh, xsa[r0 + 32], k8);
        short8 v2 = load8<EMBBF>(embf, embh, xsa[r0 + 64], k8);
        short8 v3 = zero8;
        if (real3) v3 = load8<EMBBF>(embf, embh, xsa[r0 + 96], k8);
        zw_pend = dotj(v0, ww0) + dotj(v1, ww1) + dotj(v2, ww2);
        if (real3) zw_pend += dotj(v3, ww3);
        char* base = reinterpret_cast<char*>(Es[0]);
        *reinterpret_cast<short8*>(base + (r0)      * 128 + col) = v0;
        *reinterpret_cast<short8*>(base + (r0 + 32) * 128 + col) = v1;
        *reinterpret_cast<short8*>(base + (r0 + 64) * 128 + col) = v2;
        if (has3) *reinterpret_cast<short8*>(base + (r0 + 96) * 128 + col) = v3;
    }
    __syncthreads();

    // ---- main pipelined loop over G rows ----
    for (int g = 0; g < G; ++g) {
        const int cur = g & 1;
        short8 v0 = zero8, v1 = zero8, v2 = zero8, v3 = zero8;
        if (g < G - 1) {
            const int* xg = xsa + (g + 1) * TS;
            v0 = load8<EMBBF>(embf, embh, xg[r0], k8);
            v1 = load8<EMBBF>(embf, embh, xg[r0 + 32], k8);
            v2 = load8<EMBBF>(embf, embh, xg[r0 + 64], k8);
            if (real3) v3 = load8<EMBBF>(embf, embh, xg[r0 + 96], k8);
        }

        const char* esp = reinterpret_cast<const char*>(Es[cur]) + lr * 128;
        float z = zw_pend;
        switch (wave) {
            case 0: z += fm_strip<0>(esp, c0, c1, pW2)
                       + fm_strip<4>(esp, c0, c1, pW2); break;
            case 1: z += fm_strip<1>(esp, c0, c1, pW2)
                       + fm_strip<5>(esp, c0, c1, pW2)
                       + fm_strip<6>(esp, c0, c1, pW2); break;
            case 2: z += fm_strip<2>(esp, c0, c1, pW2)
                       + deep_strip<0>(esp, wdp, c0, c1, pW3, bk0); break;
            default: z += fm_strip<3>(esp, c0, c1, pW2)
                       + deep_strip<1>(esp, wdp, c0, c1, pW3, bk1); break;
        }

        if (g < G - 1) {
            zw_pend = dotj(v0, ww0) + dotj(v1, ww1) + dotj(v2, ww2);
            if (real3) zw_pend += dotj(v3, ww3);
            char* base = reinterpret_cast<char*>(Es[cur ^ 1]);
            *reinterpret_cast<short8*>(base + (r0)      * 128 + col) = v0;
            *reinterpret_cast<short8*>(base + (r0 + 32) * 128 + col) = v1;
            *reinterpret_cast<short8*>(base + (r0 + 64) * 128 + col) = v2;
            if (has3) *reinterpret_cast<short8*>(base + (r0 + 96) * 128 + col) = v3;
        }

        #pragma unroll
        for (int off = 32; off > 0; off >>= 1) z += __shfl_down(z, off, 64);
        if (lane == 0) red[g][wave] = z;
        __syncthreads();
    }

    if (tid < G) {
        float s = red[tid][0] + red[tid][1] + red[tid][2] + red[tid][3] + b_ffn[0];
        out[b0 + tid] = 1.f / (1.f + expf(-s));
    }
}

extern "C" void kernel_launch(void* const* d_in, const int* in_sizes, int n_in,
                              void* d_out, int out_size, void* d_ws, size_t ws_size,
                              hipStream_t stream) {
    const int*   x      = (const int*)  d_in[0];
    const float* emb    = (const float*)d_in[1];
    const float* w_deep = (const float*)d_in[2];
    const float* b_deep = (const float*)d_in[3];
    const float* w_ffn  = (const float*)d_in[4];
    const float* b_ffn  = (const float*)d_in[5];
    float* out = (float*)d_out;
    const int bs = in_sizes[0] / TS;                         // 8192
    const int nblk = bs / G;                                 // 1024
    const size_t embh_bytes = (size_t)VOCAB * F * 2;         // 12.8 MB
    const size_t w2_bytes = W2_ELEMS * 4;
    const size_t w3_bytes = W3_ELEMS * 4;
    const size_t wdt_bytes = WDT_ELEMS * 2;
    const size_t wtot = w2_bytes + w3_bytes + wdt_bytes;
    const int prep_jobs = W2_ELEMS + W3_ELEMS + WDT_ELEMS;

    if (ws_size >= embh_bytes + wtot) {
        ushort* embhp = (ushort*)d_ws;
        float*  W2p   = (float*)((char*)d_ws + embh_bytes);
        float*  W3p   = (float*)((char*)d_ws + embh_bytes + w2_bytes);
        ushort* wdtp  = (ushort*)((char*)d_ws + embh_bytes + w2_bytes + w3_bytes);
        const int n8 = VOCAB * F / 8;
        hipLaunchKernelGGL(emb_cvt, dim3((n8 + 255) / 256), dim3(256), 0, stream,
                           emb, embhp, n8);
        hipLaunchKernelGGL(prep, dim3((prep_jobs + 255) / 256), dim3(256), 0, stream,
                           w_ffn, w_deep, W2p, W3p, wdtp);
        hipLaunchKernelGGL((deepfm_main<true>), dim3(nblk), dim3(256), 0, stream,
                           x, emb, embhp, W2p, W3p, wdtp, b_deep, w_ffn, b_ffn, out);
    } else {
        float*  W2p  = (float*)d_ws;
        float*  W3p  = (float*)((char*)d_ws + w2_bytes);
        ushort* wdtp = (ushort*)((char*)d_ws + w2_bytes + w3_bytes);
        hipLaunchKernelGGL(prep, dim3((prep_jobs + 255) / 256), dim3(256), 0, stream,
                           w_ffn, w_deep, W2p, W3p, wdtp);
        hipLaunchKernelGGL((deepfm_main<false>), dim3(nblk), dim3(256), 0, stream,
                           x, emb, (const ushort*)nullptr, W2p, W3p, wdtp,
                           b_deep, w_ffn, b_ffn, out);
    }
}

// Round 9
// 129.722 us; speedup vs baseline: 1.4144x; 1.4144x over previous
//
#include <hip/hip_runtime.h>
#include <cmath>
#include <cstdint>

// DeepFM R9: G=8 double-buffered pipeline with global_load_lds staging
// (zero register footprint -> no spills), linear LDS dest + pre-swizzled
// global source (inverse of the read-side XOR). Wide-dot reads LDS (R5 path).
// fm: C = E_ti x E_tj^T; z += sum C * W2[j][i] (masked i<j<TS)
// deep: C = E_tt x wdT_kt^T (M=t, N=k); z += relu(C+b).W3[k][t] (masked t<TS)
// w_ffn: deep [0,3200)=t*32+k | fm [3200,8150)=triu i<j | wide [8150,14550)=t*64+f

#define TS 100
#define F  64
#define FD 32
#define RP 112
#define G  8
#define OFF_FM 3200
#define OFF_WIDE 8150
#define VOCAB 100000
#define W2_ELEMS (RP*RP)      // [j:112][i:112] fp32
#define W3_ELEMS (FD*RP)      // [k:32][t:112] fp32
#define WDT_ELEMS (FD*F)      // [k:32][f:64] bf16
#define ESTRIDE (RP*F)        // ushorts per Es buffer (14336 B)
#define N8 (VOCAB*F/8)        // 800000 cvt jobs

typedef __attribute__((ext_vector_type(8))) short short8;
typedef __attribute__((ext_vector_type(4))) float f32x4;

__device__ __forceinline__ ushort f2bf(float x) {
    uint u = __float_as_uint(x);
    u = (u + 0x7FFFu + ((u >> 16) & 1u)) >> 16;
    return (ushort)u;
}
__device__ __forceinline__ float bf2f(ushort h) {
    return __uint_as_float((uint)h << 16);
}
__device__ __forceinline__ short8 pack8(float4 a, float4 b) {
    short8 r;
    r[0] = (short)f2bf(a.x); r[1] = (short)f2bf(a.y);
    r[2] = (short)f2bf(a.z); r[3] = (short)f2bf(a.w);
    r[4] = (short)f2bf(b.x); r[5] = (short)f2bf(b.y);
    r[6] = (short)f2bf(b.z); r[7] = (short)f2bf(b.w);
    return r;
}

// async 16B global -> LDS (CK-style addrspace casts via uintptr_t)
__device__ __forceinline__ void gload_lds16(const void* g, void* l) {
    auto gp = reinterpret_cast<const uint __attribute__((address_space(1)))*>(
        reinterpret_cast<uintptr_t>(g));
    auto lp = reinterpret_cast<uint __attribute__((address_space(3)))*>(
        reinterpret_cast<uintptr_t>(l));
    __builtin_amdgcn_global_load_lds(gp, lp, 16, 0, 0);
}

// one kernel: bf16 emb conversion (i < n8) + weight-matrix prep (i >= n8)
__global__ __launch_bounds__(256)
void prep_all(const float* __restrict__ emb, ushort* __restrict__ embh,
              const float* __restrict__ w_ffn, const float* __restrict__ w_deep,
              float* __restrict__ W2, float* __restrict__ W3,
              ushort* __restrict__ wdt, int n8) {
    int i = blockIdx.x * 256 + threadIdx.x;
    if (i < n8) {
        const float4* s = reinterpret_cast<const float4*>(emb) + (size_t)i * 2;
        reinterpret_cast<short8*>(embh)[i] = pack8(s[0], s[1]);
        return;
    }
    int j = i - n8;
    if (j < W2_ELEMS) {
        int jc = j / RP, ii = j % RP;
        float v = 0.f;
        if (ii < jc && jc < TS)
            v = w_ffn[OFF_FM + ii * (199 - ii) / 2 + (jc - ii - 1)];
        W2[j] = v;
    } else if (j < W2_ELEMS + W3_ELEMS) {
        int q = j - W2_ELEMS;
        int k = q / RP, t = q % RP;
        W3[q] = (t < TS) ? w_ffn[t * FD + k] : 0.f;
    } else if (j < W2_ELEMS + W3_ELEMS + WDT_ELEMS) {
        int q = j - W2_ELEMS - W3_ELEMS;
        int k = q >> 6, f = q & 63;
        wdt[q] = f2bf(w_deep[f * FD + k]);
    }
}

// fm strip: A = E rows TI*16 (persistent); tiles tj=TI..6; diag reuses A as B.
template<int TI>
__device__ __forceinline__ float fm_strip(const char* esp, int c0, int c1,
                                          const float* pW2) {
    short8 A0 = *reinterpret_cast<const short8*>(esp + TI * 2048 + c0);
    short8 A1 = *reinterpret_cast<const short8*>(esp + TI * 2048 + c1);
    float z = 0.f;
    #pragma unroll
    for (int tj = TI; tj < 7; ++tj) {
        short8 B0, B1;
        if (tj == TI) { B0 = A0; B1 = A1; }
        else {
            B0 = *reinterpret_cast<const short8*>(esp + tj * 2048 + c0);
            B1 = *reinterpret_cast<const short8*>(esp + tj * 2048 + c1);
        }
        f32x4 acc = {0.f, 0.f, 0.f, 0.f};
        acc = __builtin_amdgcn_mfma_f32_16x16x32_bf16(A0, B0, acc, 0, 0, 0);
        acc = __builtin_amdgcn_mfma_f32_16x16x32_bf16(A1, B1, acc, 0, 0, 0);
        float4 w = *reinterpret_cast<const float4*>(pW2 + tj * 1792 + TI * 16);
        z += acc[0] * w.x + acc[1] * w.y + acc[2] * w.z + acc[3] * w.w;
    }
    return z;
}

// deep strip: B = wdT rows KT*16 (persistent); A = E rows tt (M=t, N=k).
template<int KT>
__device__ __forceinline__ float deep_strip(const char* esp, const char* wdp,
                                            int c0, int c1, const float* pW3,
                                            float bk) {
    short8 B0 = *reinterpret_cast<const short8*>(wdp + KT * 2048 + c0);
    short8 B1 = *reinterpret_cast<const short8*>(wdp + KT * 2048 + c1);
    float z = 0.f;
    #pragma unroll
    for (int tt = 0; tt < 7; ++tt) {
        short8 A0 = *reinterpret_cast<const short8*>(esp + tt * 2048 + c0);
        short8 A1 = *reinterpret_cast<const short8*>(esp + tt * 2048 + c1);
        f32x4 acc = {0.f, 0.f, 0.f, 0.f};
        acc = __builtin_amdgcn_mfma_f32_16x16x32_bf16(A0, B0, acc, 0, 0, 0);
        acc = __builtin_amdgcn_mfma_f32_16x16x32_bf16(A1, B1, acc, 0, 0, 0);
        float4 w = *reinterpret_cast<const float4*>(pW3 + KT * 1792 + tt * 16);
        z += fmaxf(acc[0] + bk, 0.f) * w.x + fmaxf(acc[1] + bk, 0.f) * w.y
           + fmaxf(acc[2] + bk, 0.f) * w.z + fmaxf(acc[3] + bk, 0.f) * w.w;
    }
    return z;
}

template<bool EMBBF>
__global__ __launch_bounds__(256)
void deepfm_main(const int* __restrict__ x,
                 const float* __restrict__ embf,
                 const ushort* __restrict__ embh,
                 const float* __restrict__ W2,
                 const float* __restrict__ W3,
                 const ushort* __restrict__ wdt,
                 const float* __restrict__ b_deep,
                 const float* __restrict__ w_ffn,
                 const float* __restrict__ b_ffn,
                 float* __restrict__ out)
{
    __shared__ ushort Es[2][ESTRIDE];   // 2x14336B; physical col = (k8^(r&7))*16
    __shared__ ushort wdT[FD * F];
    __shared__ int    xsa[G * TS];
    __shared__ float  red[G][4];

    const int tid  = threadIdx.x;
    const int lane = tid & 63;
    const int wave = tid >> 6;
    const int lr   = lane & 15;
    const int lg   = lane >> 4;
    const int b0   = blockIdx.x * G;

    for (int j = tid; j < G * TS; j += 256) xsa[j] = x[(size_t)b0 * TS + j];
    {   // stage prepped wdt -> LDS, swizzled
        int k = tid >> 3, k8 = tid & 7;
        int col = (k8 * 16) ^ ((k & 7) << 4);
        *reinterpret_cast<short8*>(reinterpret_cast<char*>(wdT) + k * 128 + col)
            = *reinterpret_cast<const short8*>(wdt + k * F + k8 * 8);
    }
    if (tid < 192) {   // zero pad rows 100..111 of both buffers (once; loads never touch them)
        int buf = tid / 96, q = tid % 96;
        int r = 100 + (q >> 3), k8 = q & 7;
        const short8 z8 = {0, 0, 0, 0, 0, 0, 0, 0};
        *reinterpret_cast<short8*>(reinterpret_cast<char*>(Es[buf]) + r * 128 + k8 * 16) = z8;
    }
    __syncthreads();

    // staging geometry: thread handles rows r0,+32,+64,(+96 if real), LDS linear slot k8lin
    const int k8lin = tid & 7;
    const int r0    = tid >> 3;               // 0..31; rows' low3 bits == r0&7
    const int k8src = k8lin ^ (r0 & 7);       // pre-swizzled global column
    const int wb    = wave * 1024;            // wave-uniform LDS base offset

    // fragment/epilogue bases
    const int c0 = (lg * 16) ^ ((lr & 7) << 4);
    const int c1 = (64 + lg * 16) ^ ((lr & 7) << 4);
    const char* wdp = reinterpret_cast<const char*>(wdT) + lr * 128;
    const float* pW2 = W2 + lr * RP + lg * 4;
    const float* pW3 = W3 + lr * RP + lg * 4;
    const float bk0 = b_deep[lr];
    const float bk1 = b_deep[16 + lr];

    auto stage_async = [&](ushort* buf, const int* xg) {
        char* base = reinterpret_cast<char*>(buf) + wb;
        gload_lds16(embh + (size_t)xg[r0] * F + k8src * 8, base);
        gload_lds16(embh + (size_t)xg[r0 + 32] * F + k8src * 8, base + 4096);
        gload_lds16(embh + (size_t)xg[r0 + 64] * F + k8src * 8, base + 8192);
        if (r0 < 4)  // rows 96..99 only
            gload_lds16(embh + (size_t)xg[r0 + 96] * F + k8src * 8, base + 12288);
    };
    auto stage_sync = [&](ushort* buf, const int* xg) {   // fp32 fallback
        const int col = (k8lin * 16) ^ ((r0 & 7) << 4);
        char* base = reinterpret_cast<char*>(buf);
        #pragma unroll
        for (int jb = 0; jb < 4; ++jb) {
            int r = r0 + 32 * jb;
            if (r < TS) {
                const float* s = embf + (size_t)xg[r] * F + k8lin * 8;
                float4 a = reinterpret_cast<const float4*>(s)[0];
                float4 c = reinterpret_cast<const float4*>(s)[1];
                *reinterpret_cast<short8*>(base + r * 128 + col) = pack8(a, c);
            }
        }
    };
    auto compute_row = [&](const ushort* buf) -> float {
        const char* esp = reinterpret_cast<const char*>(buf) + lr * 128;
        float z = 0.f;
        switch (wave) {
            case 0: z += fm_strip<0>(esp, c0, c1, pW2)
                       + fm_strip<4>(esp, c0, c1, pW2); break;
            case 1: z += fm_strip<1>(esp, c0, c1, pW2)
                       + fm_strip<5>(esp, c0, c1, pW2)
                       + fm_strip<6>(esp, c0, c1, pW2); break;
            case 2: z += fm_strip<2>(esp, c0, c1, pW2)
                       + deep_strip<0>(esp, wdp, c0, c1, pW3, bk0); break;
            default: z += fm_strip<3>(esp, c0, c1, pW2)
                       + deep_strip<1>(esp, wdp, c0, c1, pW3, bk1); break;
        }
        // wide: e_flat . w_wide (800 jobs x 8 elems; w only 8B-aligned -> float2)
        for (int j = tid; j < TS * 8; j += 256) {
            int t = j >> 3, k8 = j & 7;
            int off = (k8 * 16) ^ ((t & 7) << 4);
            short8 v = *reinterpret_cast<const short8*>(
                reinterpret_cast<const char*>(buf) + t * 128 + off);
            const float2* w2p = reinterpret_cast<const float2*>(
                w_ffn + OFF_WIDE + t * F + k8 * 8);
            float2 wa = w2p[0], wb2 = w2p[1], wc = w2p[2], wd = w2p[3];
            z += bf2f((ushort)v[0]) * wa.x + bf2f((ushort)v[1]) * wa.y
               + bf2f((ushort)v[2]) * wb2.x + bf2f((ushort)v[3]) * wb2.y
               + bf2f((ushort)v[4]) * wc.x + bf2f((ushort)v[5]) * wc.y
               + bf2f((ushort)v[6]) * wd.x + bf2f((ushort)v[7]) * wd.y;
        }
        return z;
    };

    if constexpr (EMBBF) {
        stage_async(Es[0], xsa);
        __syncthreads();
        for (int g = 0; g < G; ++g) {
            const int cur = g & 1;
            if (g < G - 1) stage_async(Es[cur ^ 1], xsa + (g + 1) * TS);
            float z = compute_row(Es[cur]);
            #pragma unroll
            for (int off = 32; off > 0; off >>= 1) z += __shfl_down(z, off, 64);
            if (lane == 0) red[g][wave] = z;
            __syncthreads();   // drains async loads (vmcnt) + compute
        }
    } else {
        for (int g = 0; g < G; ++g) {
            if (g > 0) __syncthreads();
            stage_sync(Es[0], xsa + g * TS);
            __syncthreads();
            float z = compute_row(Es[0]);
            #pragma unroll
            for (int off = 32; off > 0; off >>= 1) z += __shfl_down(z, off, 64);
            if (lane == 0) red[g][wave] = z;
        }
        __syncthreads();
    }

    if (tid < G) {
        float s = red[tid][0] + red[tid][1] + red[tid][2] + red[tid][3] + b_ffn[0];
        out[b0 + tid] = 1.f / (1.f + expf(-s));
    }
}

extern "C" void kernel_launch(void* const* d_in, const int* in_sizes, int n_in,
                              void* d_out, int out_size, void* d_ws, size_t ws_size,
                              hipStream_t stream) {
    const int*   x      = (const int*)  d_in[0];
    const float* emb    = (const float*)d_in[1];
    const float* w_deep = (const float*)d_in[2];
    const float* b_deep = (const float*)d_in[3];
    const float* w_ffn  = (const float*)d_in[4];
    const float* b_ffn  = (const float*)d_in[5];
    float* out = (float*)d_out;
    const int bs = in_sizes[0] / TS;                         // 8192
    const int nblk = bs / G;                                 // 1024
    const size_t embh_bytes = (size_t)VOCAB * F * 2;         // 12.8 MB
    const size_t w2_bytes = W2_ELEMS * 4;
    const size_t w3_bytes = W3_ELEMS * 4;
    const size_t wdt_bytes = WDT_ELEMS * 2;
    const size_t wtot = w2_bytes + w3_bytes + wdt_bytes;
    const int prep_jobs = W2_ELEMS + W3_ELEMS + WDT_ELEMS;   // 18176

    if (ws_size >= embh_bytes + wtot) {
        ushort* embhp = (ushort*)d_ws;
        float*  W2p   = (float*)((char*)d_ws + embh_bytes);
        float*  W3p   = (float*)((char*)d_ws + embh_bytes + w2_bytes);
        ushort* wdtp  = (ushort*)((char*)d_ws + embh_bytes + w2_bytes + w3_bytes);
        const int total = N8 + prep_jobs;
        hipLaunchKernelGGL(prep_all, dim3((total + 255) / 256), dim3(256), 0, stream,
                           emb, embhp, w_ffn, w_deep, W2p, W3p, wdtp, N8);
        hipLaunchKernelGGL((deepfm_main<true>), dim3(nblk), dim3(256), 0, stream,
                           x, emb, embhp, W2p, W3p, wdtp, b_deep, w_ffn, b_ffn, out);
    } else {
        float*  W2p  = (float*)d_ws;
        float*  W3p  = (float*)((char*)d_ws + w2_bytes);
        ushort* wdtp = (ushort*)((char*)d_ws + w2_bytes + w3_bytes);
        hipLaunchKernelGGL(prep_all, dim3((prep_jobs + 255) / 256), dim3(256), 0, stream,
                           emb, (ushort*)nullptr, w_ffn, w_deep, W2p, W3p, wdtp, 0);
        hipLaunchKernelGGL((deepfm_main<false>), dim3(nblk), dim3(256), 0, stream,
                           x, emb, (const ushort*)nullptr, W2p, W3p, wdtp,
                           b_deep, w_ffn, b_ffn, out);
    }
}

// Round 10
// 128.179 us; speedup vs baseline: 1.4314x; 1.0120x over previous
//
#include <hip/hip_runtime.h>
#include <cmath>
#include <cstdint>

// DeepFM R10 = R9 + 32-row-strip fragment reuse (LDS-read traffic cut ~35%).
// fm: C = E_ti x E_tj^T; z += sum C * W2[j][i] (masked i<j<TS)
// deep: C = E_tt x wdT_kt^T (M=t, N=k); z += relu(C+b).W3[k][t] (masked t<TS)
// w_ffn: deep [0,3200)=t*32+k | fm [3200,8150)=triu i<j | wide [8150,14550)=t*64+f

#define TS 100
#define F  64
#define FD 32
#define RP 112
#define G  8
#define OFF_FM 3200
#define OFF_WIDE 8150
#define VOCAB 100000
#define W2_ELEMS (RP*RP)      // [j:112][i:112] fp32
#define W3_ELEMS (FD*RP)      // [k:32][t:112] fp32
#define WDT_ELEMS (FD*F)      // [k:32][f:64] bf16
#define ESTRIDE (RP*F)        // ushorts per Es buffer (14336 B)
#define N8 (VOCAB*F/8)        // 800000 cvt jobs

typedef __attribute__((ext_vector_type(8))) short short8;
typedef __attribute__((ext_vector_type(4))) float f32x4;

__device__ __forceinline__ ushort f2bf(float x) {
    uint u = __float_as_uint(x);
    u = (u + 0x7FFFu + ((u >> 16) & 1u)) >> 16;
    return (ushort)u;
}
__device__ __forceinline__ float bf2f(ushort h) {
    return __uint_as_float((uint)h << 16);
}
__device__ __forceinline__ short8 pack8(float4 a, float4 b) {
    short8 r;
    r[0] = (short)f2bf(a.x); r[1] = (short)f2bf(a.y);
    r[2] = (short)f2bf(a.z); r[3] = (short)f2bf(a.w);
    r[4] = (short)f2bf(b.x); r[5] = (short)f2bf(b.y);
    r[6] = (short)f2bf(b.z); r[7] = (short)f2bf(b.w);
    return r;
}

// async 16B global -> LDS
__device__ __forceinline__ void gload_lds16(const void* g, void* l) {
    auto gp = reinterpret_cast<const uint __attribute__((address_space(1)))*>(
        reinterpret_cast<uintptr_t>(g));
    auto lp = reinterpret_cast<uint __attribute__((address_space(3)))*>(
        reinterpret_cast<uintptr_t>(l));
    __builtin_amdgcn_global_load_lds(gp, lp, 16, 0, 0);
}

__global__ __launch_bounds__(256)
void prep_all(const float* __restrict__ emb, ushort* __restrict__ embh,
              const float* __restrict__ w_ffn, const float* __restrict__ w_deep,
              float* __restrict__ W2, float* __restrict__ W3,
              ushort* __restrict__ wdt, int n8) {
    int i = blockIdx.x * 256 + threadIdx.x;
    if (i < n8) {
        const float4* s = reinterpret_cast<const float4*>(emb) + (size_t)i * 2;
        reinterpret_cast<short8*>(embh)[i] = pack8(s[0], s[1]);
        return;
    }
    int j = i - n8;
    if (j < W2_ELEMS) {
        int jc = j / RP, ii = j % RP;
        float v = 0.f;
        if (ii < jc && jc < TS)
            v = w_ffn[OFF_FM + ii * (199 - ii) / 2 + (jc - ii - 1)];
        W2[j] = v;
    } else if (j < W2_ELEMS + W3_ELEMS) {
        int q = j - W2_ELEMS;
        int k = q / RP, t = q % RP;
        W3[q] = (t < TS) ? w_ffn[t * FD + k] : 0.f;
    } else if (j < W2_ELEMS + W3_ELEMS + WDT_ELEMS) {
        int q = j - W2_ELEMS - W3_ELEMS;
        int k = q >> 6, f = q & 63;
        wdt[q] = f2bf(w_deep[f * FD + k]);
    }
}

#define MFMA __builtin_amdgcn_mfma_f32_16x16x32_bf16

__device__ __forceinline__ float dot4(f32x4 a, float4 w) {
    return a[0] * w.x + a[1] * w.y + a[2] * w.z + a[3] * w.w;
}

// fm 32-row strip: A-tiles TI0,TI0+1 persistent; B loops tj=TI0..6 (read once,
// used by both row-tiles); diag tiles reuse A as B. W2 masks i>=j and pads.
template<int TI0>
__device__ __forceinline__ float fm32(const char* esp, int c0, int c1,
                                      const float* pW2) {
    short8 Aa0 = *reinterpret_cast<const short8*>(esp + TI0 * 2048 + c0);
    short8 Aa1 = *reinterpret_cast<const short8*>(esp + TI0 * 2048 + c1);
    short8 Ab0 = *reinterpret_cast<const short8*>(esp + (TI0 + 1) * 2048 + c0);
    short8 Ab1 = *reinterpret_cast<const short8*>(esp + (TI0 + 1) * 2048 + c1);
    float z = 0.f;
    #pragma unroll
    for (int tj = TI0; tj < 7; ++tj) {
        short8 B0, B1;
        if (tj == TI0)          { B0 = Aa0; B1 = Aa1; }
        else if (tj == TI0 + 1) { B0 = Ab0; B1 = Ab1; }
        else {
            B0 = *reinterpret_cast<const short8*>(esp + tj * 2048 + c0);
            B1 = *reinterpret_cast<const short8*>(esp + tj * 2048 + c1);
        }
        f32x4 aca = {0.f, 0.f, 0.f, 0.f};
        aca = MFMA(Aa0, B0, aca, 0, 0, 0);
        aca = MFMA(Aa1, B1, aca, 0, 0, 0);
        z += dot4(aca, *reinterpret_cast<const float4*>(pW2 + tj * 1792 + TI0 * 16));
        if (tj > TI0) {
            f32x4 acb = {0.f, 0.f, 0.f, 0.f};
            acb = MFMA(Ab0, B0, acb, 0, 0, 0);
            acb = MFMA(Ab1, B1, acb, 0, 0, 0);
            z += dot4(acb, *reinterpret_cast<const float4*>(pW2 + tj * 1792 + (TI0 + 1) * 16));
        }
    }
    return z;
}

// single diagonal tile 6 (rows 96-111; pads are zero, W2 masks)
__device__ __forceinline__ float fm16d(const char* esp, int c0, int c1,
                                       const float* pW2) {
    short8 A0 = *reinterpret_cast<const short8*>(esp + 6 * 2048 + c0);
    short8 A1 = *reinterpret_cast<const short8*>(esp + 6 * 2048 + c1);
    f32x4 acc = {0.f, 0.f, 0.f, 0.f};
    acc = MFMA(A0, A0, acc, 0, 0, 0);
    acc = MFMA(A1, A1, acc, 0, 0, 0);
    return dot4(acc, *reinterpret_cast<const float4*>(pW2 + 6 * 1792 + 6 * 16));
}

// deep over t-tiles [T0,T1): both kt B-pairs loaded once; A per t-tile.
template<int T0, int T1>
__device__ __forceinline__ float deep_range(const char* esp, const char* wdp,
                                            int c0, int c1, const float* pW3,
                                            float bk0, float bk1) {
    short8 Ba0 = *reinterpret_cast<const short8*>(wdp + c0);
    short8 Ba1 = *reinterpret_cast<const short8*>(wdp + c1);
    short8 Bb0 = *reinterpret_cast<const short8*>(wdp + 2048 + c0);
    short8 Bb1 = *reinterpret_cast<const short8*>(wdp + 2048 + c1);
    float z = 0.f;
    #pragma unroll
    for (int ts = T0; ts < T1; ++ts) {
        short8 A0 = *reinterpret_cast<const short8*>(esp + ts * 2048 + c0);
        short8 A1 = *reinterpret_cast<const short8*>(esp + ts * 2048 + c1);
        f32x4 a0 = {0.f, 0.f, 0.f, 0.f};
        a0 = MFMA(A0, Ba0, a0, 0, 0, 0);
        a0 = MFMA(A1, Ba1, a0, 0, 0, 0);
        f32x4 a1 = {0.f, 0.f, 0.f, 0.f};
        a1 = MFMA(A0, Bb0, a1, 0, 0, 0);
        a1 = MFMA(A1, Bb1, a1, 0, 0, 0);
        float4 w0 = *reinterpret_cast<const float4*>(pW3 + ts * 16);
        float4 w1 = *reinterpret_cast<const float4*>(pW3 + 1792 + ts * 16);
        z += fmaxf(a0[0] + bk0, 0.f) * w0.x + fmaxf(a0[1] + bk0, 0.f) * w0.y
           + fmaxf(a0[2] + bk0, 0.f) * w0.z + fmaxf(a0[3] + bk0, 0.f) * w0.w
           + fmaxf(a1[0] + bk1, 0.f) * w1.x + fmaxf(a1[1] + bk1, 0.f) * w1.y
           + fmaxf(a1[2] + bk1, 0.f) * w1.z + fmaxf(a1[3] + bk1, 0.f) * w1.w;
    }
    return z;
}

template<bool EMBBF>
__global__ __launch_bounds__(256)
void deepfm_main(const int* __restrict__ x,
                 const float* __restrict__ embf,
                 const ushort* __restrict__ embh,
                 const float* __restrict__ W2,
                 const float* __restrict__ W3,
                 const ushort* __restrict__ wdt,
                 const float* __restrict__ b_deep,
                 const float* __restrict__ w_ffn,
                 const float* __restrict__ b_ffn,
                 float* __restrict__ out)
{
    __shared__ ushort Es[2][ESTRIDE];   // 2x14336B; physical col = (k8^(r&7))*16
    __shared__ ushort wdT[FD * F];
    __shared__ int    xsa[G * TS];
    __shared__ float  red[G][4];

    const int tid  = threadIdx.x;
    const int lane = tid & 63;
    const int wave = tid >> 6;
    const int lr   = lane & 15;
    const int lg   = lane >> 4;
    const int b0   = blockIdx.x * G;

    for (int j = tid; j < G * TS; j += 256) xsa[j] = x[(size_t)b0 * TS + j];
    {   // stage prepped wdt -> LDS, swizzled
        int k = tid >> 3, k8 = tid & 7;
        int col = (k8 * 16) ^ ((k & 7) << 4);
        *reinterpret_cast<short8*>(reinterpret_cast<char*>(wdT) + k * 128 + col)
            = *reinterpret_cast<const short8*>(wdt + k * F + k8 * 8);
    }
    if (tid < 192) {   // zero pad rows 100..111 once (staging never writes them)
        int buf = tid / 96, q = tid % 96;
        int r = 100 + (q >> 3), k8 = q & 7;
        const short8 z8 = {0, 0, 0, 0, 0, 0, 0, 0};
        *reinterpret_cast<short8*>(reinterpret_cast<char*>(Es[buf]) + r * 128 + k8 * 16) = z8;
    }
    __syncthreads();

    // staging geometry: thread handles rows r0,+32,+64,(+96 if real), slot k8lin
    const int k8lin = tid & 7;
    const int r0    = tid >> 3;
    const int k8src = k8lin ^ (r0 & 7);       // pre-swizzled global column
    const int wb    = wave * 1024;            // wave-uniform LDS base offset

    const int c0 = (lg * 16) ^ ((lr & 7) << 4);
    const int c1 = (64 + lg * 16) ^ ((lr & 7) << 4);
    const char* wdp = reinterpret_cast<const char*>(wdT) + lr * 128;
    const float* pW2 = W2 + lr * RP + lg * 4;
    const float* pW3 = W3 + lr * RP + lg * 4;
    const float bk0 = b_deep[lr];
    const float bk1 = b_deep[16 + lr];

    auto stage_async = [&](ushort* buf, const int* xg) {
        char* base = reinterpret_cast<char*>(buf) + wb;
        gload_lds16(embh + (size_t)xg[r0] * F + k8src * 8, base);
        gload_lds16(embh + (size_t)xg[r0 + 32] * F + k8src * 8, base + 4096);
        gload_lds16(embh + (size_t)xg[r0 + 64] * F + k8src * 8, base + 8192);
        if (r0 < 4)
            gload_lds16(embh + (size_t)xg[r0 + 96] * F + k8src * 8, base + 12288);
    };
    auto stage_sync = [&](ushort* buf, const int* xg) {   // fp32 fallback
        const int col = (k8lin * 16) ^ ((r0 & 7) << 4);
        char* base = reinterpret_cast<char*>(buf);
        #pragma unroll
        for (int jb = 0; jb < 4; ++jb) {
            int r = r0 + 32 * jb;
            if (r < TS) {
                const float* s = embf + (size_t)xg[r] * F + k8lin * 8;
                float4 a = reinterpret_cast<const float4*>(s)[0];
                float4 c = reinterpret_cast<const float4*>(s)[1];
                *reinterpret_cast<short8*>(base + r * 128 + col) = pack8(a, c);
            }
        }
    };
    auto compute_row = [&](const ushort* buf) -> float {
        const char* esp = reinterpret_cast<const char*>(buf) + lr * 128;
        float z = 0.f;
        switch (wave) {
            case 0: z += fm32<0>(esp, c0, c1, pW2); break;                       // 13 tiles
            case 1: z += fm32<2>(esp, c0, c1, pW2)
                       + fm16d(esp, c0, c1, pW2); break;                         // 10
            case 2: z += fm32<4>(esp, c0, c1, pW2)
                       + deep_range<0, 2>(esp, wdp, c0, c1, pW3, bk0, bk1); break; // 9
            default: z += deep_range<2, 7>(esp, wdp, c0, c1, pW3, bk0, bk1); break; // 10
        }
        // wide: e_flat . w_wide (800 jobs x 8 elems; w only 8B-aligned -> float2)
        for (int j = tid; j < TS * 8; j += 256) {
            int t = j >> 3, k8 = j & 7;
            int off = (k8 * 16) ^ ((t & 7) << 4);
            short8 v = *reinterpret_cast<const short8*>(
                reinterpret_cast<const char*>(buf) + t * 128 + off);
            const float2* w2p = reinterpret_cast<const float2*>(
                w_ffn + OFF_WIDE + t * F + k8 * 8);
            float2 wa = w2p[0], wb2 = w2p[1], wc = w2p[2], wd = w2p[3];
            z += bf2f((ushort)v[0]) * wa.x + bf2f((ushort)v[1]) * wa.y
               + bf2f((ushort)v[2]) * wb2.x + bf2f((ushort)v[3]) * wb2.y
               + bf2f((ushort)v[4]) * wc.x + bf2f((ushort)v[5]) * wc.y
               + bf2f((ushort)v[6]) * wd.x + bf2f((ushort)v[7]) * wd.y;
        }
        return z;
    };

    if constexpr (EMBBF) {
        stage_async(Es[0], xsa);
        __syncthreads();
        for (int g = 0; g < G; ++g) {
            const int cur = g & 1;
            if (g < G - 1) stage_async(Es[cur ^ 1], xsa + (g + 1) * TS);
            float z = compute_row(Es[cur]);
            #pragma unroll
            for (int off = 32; off > 0; off >>= 1) z += __shfl_down(z, off, 64);
            if (lane == 0) red[g][wave] = z;
            __syncthreads();   // drains async loads + compute
        }
    } else {
        for (int g = 0; g < G; ++g) {
            if (g > 0) __syncthreads();
            stage_sync(Es[0], xsa + g * TS);
            __syncthreads();
            float z = compute_row(Es[0]);
            #pragma unroll
            for (int off = 32; off > 0; off >>= 1) z += __shfl_down(z, off, 64);
            if (lane == 0) red[g][wave] = z;
        }
        __syncthreads();
    }

    if (tid < G) {
        float s = red[tid][0] + red[tid][1] + red[tid][2] + red[tid][3] + b_ffn[0];
        out[b0 + tid] = 1.f / (1.f + expf(-s));
    }
}

extern "C" void kernel_launch(void* const* d_in, const int* in_sizes, int n_in,
                              void* d_out, int out_size, void* d_ws, size_t ws_size,
                              hipStream_t stream) {
    const int*   x      = (const int*)  d_in[0];
    const float* emb    = (const float*)d_in[1];
    const float* w_deep = (const float*)d_in[2];
    const float* b_deep = (const float*)d_in[3];
    const float* w_ffn  = (const float*)d_in[4];
    const float* b_ffn  = (const float*)d_in[5];
    float* out = (float*)d_out;
    const int bs = in_sizes[0] / TS;                         // 8192
    const int nblk = bs / G;                                 // 1024
    const size_t embh_bytes = (size_t)VOCAB * F * 2;         // 12.8 MB
    const size_t w2_bytes = W2_ELEMS * 4;
    const size_t w3_bytes = W3_ELEMS * 4;
    const size_t wdt_bytes = WDT_ELEMS * 2;
    const size_t wtot = w2_bytes + w3_bytes + wdt_bytes;
    const int prep_jobs = W2_ELEMS + W3_ELEMS + WDT_ELEMS;   // 18176

    if (ws_size >= embh_bytes + wtot) {
        ushort* embhp = (ushort*)d_ws;
        float*  W2p   = (float*)((char*)d_ws + embh_bytes);
        float*  W3p   = (float*)((char*)d_ws + embh_bytes + w2_bytes);
        ushort* wdtp  = (ushort*)((char*)d_ws + embh_bytes + w2_bytes + w3_bytes);
        const int total = N8 + prep_jobs;
        hipLaunchKernelGGL(prep_all, dim3((total + 255) / 256), dim3(256), 0, stream,
                           emb, embhp, w_ffn, w_deep, W2p, W3p, wdtp, N8);
        hipLaunchKernelGGL((deepfm_main<true>), dim3(nblk), dim3(256), 0, stream,
                           x, emb, embhp, W2p, W3p, wdtp, b_deep, w_ffn, b_ffn, out);
    } else {
        float*  W2p  = (float*)d_ws;
        float*  W3p  = (float*)((char*)d_ws + w2_bytes);
        ushort* wdtp = (ushort*)((char*)d_ws + w2_bytes + w3_bytes);
        hipLaunchKernelGGL(prep_all, dim3((prep_jobs + 255) / 256), dim3(256), 0, stream,
                           emb, (ushort*)nullptr, w_ffn, w_deep, W2p, W3p, wdtp, 0);
        hipLaunchKernelGGL((deepfm_main<false>), dim3(nblk), dim3(256), 0, stream,
                           x, emb, (const ushort*)nullptr, W2p, W3p, wdtp,
                           b_deep, w_ffn, b_ffn, out);
    }
}